// Round 12
// baseline (197.288 us; speedup 1.0000x reference)
//
#include <hip/hip_runtime.h>
#include <math.h>

typedef _Float16 f16;
typedef f16 f16x8 __attribute__((ext_vector_type(8)));
typedef float f32x4 __attribute__((ext_vector_type(4)));

#define NT    16384
#define DIM   4096
#define NEXP  128
#define TOPK  8
#define NFLAT (NT * TOPK)   // 131072
#define SBLK  512           // sort blocks (256 sel entries each)
#define KS    2             // split-K
#define KPER  (DIM / KS)    // 2048
#define BK    64
#define NST   (KPER / BK)   // 32 steps per block
#define BT    64            // tokens per gemm block

// ---- workspace layout (bytes) ----
#define COUNTS_OFF 0
#define SEL_OFF    1024
#define WGT_OFF    (SEL_OFF + NFLAT * 4)
#define BH_OFF     (WGT_OFF + NFLAT * 4)
#define BO_OFF     (BH_OFF + NEXP * SBLK * 4)
#define WPK_OFF    (BO_OFF + NEXP * SBLK * 4)    // 2 MB packed W
#define PART_OFF   (WPK_OFF + NEXP * DIM * 4)    // 16.8 MB partials

#define G1P __attribute__((address_space(1)))
#define L3P __attribute__((address_space(3)))

__device__ __forceinline__ void gload_lds16(const void* g, void* l) {
    // LDS dest = wave-uniform base + lane*16 (HW); global src = per-lane
    __builtin_amdgcn_global_load_lds((const G1P unsigned int*)g,
                                     (L3P unsigned int*)l, 16, 0, 0);
}

// fp32 -> fp16 high + scaled residual (next ~11 mantissa bits, normal range)
__device__ __forceinline__ void split2(float v, f16& h, f16& m) {
    h = (f16)v;
    m = (f16)((v - (float)h) * 2048.0f);
}

// ============ prologue: pack 64*gw into fragment-ordered f16 chunks ============
// wpk[(st*8+g)*4096 + c*1024 + lane*16]: c0=h,kk0 c1=h,kk1 c2=m,kk0 c3=m,kk1
// content(lane l) = halves of 64*gw[g*16+(l&15)][st*64 + kk*32 + (l>>4)*8 ..+7]
__global__ __launch_bounds__(256)
void wsplit_kernel(const float* __restrict__ gw, char* __restrict__ wpk) {
    const int t = blockIdx.x * 256 + threadIdx.x;    // 65536 threads
    const int l = t & 63, kkc = (t >> 6) & 1, g = (t >> 7) & 7, st = t >> 10;
    const int e = g * 16 + (l & 15);
    const int k0 = st * 64 + kkc * 32 + (l >> 4) * 8;
    float4 a = *(const float4*)&gw[e * 4096 + k0];
    float4 b = *(const float4*)&gw[e * 4096 + k0 + 4];
    union { f16 f[8]; uint4 u; } ph, pm;
    split2(a.x * 64.f, ph.f[0], pm.f[0]); split2(a.y * 64.f, ph.f[1], pm.f[1]);
    split2(a.z * 64.f, ph.f[2], pm.f[2]); split2(a.w * 64.f, ph.f[3], pm.f[3]);
    split2(b.x * 64.f, ph.f[4], pm.f[4]); split2(b.y * 64.f, ph.f[5], pm.f[5]);
    split2(b.z * 64.f, ph.f[6], pm.f[6]); split2(b.w * 64.f, ph.f[7], pm.f[7]);
    const size_t base = ((size_t)(st * 8 + g) * 4 + kkc) * 1024 + l * 16;
    *(uint4*)(wpk + base)        = ph.u;
    *(uint4*)(wpk + base + 2048) = pm.u;
}

// ============ GEMM: partial[ks][tok][e], R9 dataflow @ 2 blocks/CU ============
// 512 blocks = 256 token-tiles x 2 K-slices; 512 thr (8 waves = 2 tok-grp x
// 4 exp-grp), wave tile 32 tok x 32 exp, 32 K-steps of 64.
// W: LDS dbuf 64KB via coalesced global_load_lds from packed wpk (L2).
// A: direct global->VGPR gather (x read once from HBM), h/m split in regs.
// One s_barrier + counted vmcnt(8) per step (never 0 in main loop).
__global__ __launch_bounds__(512, 4)
void gemm_kernel(const float* __restrict__ x, const char* __restrict__ wpk,
                 float* __restrict__ partial) {
    __shared__ __align__(16) char WB[65536];

    const int tid  = threadIdx.x;
    const int bid  = blockIdx.x;
    const int ks   = bid & 1;
    const int tok0 = (bid >> 1) * BT;
    const int lane = tid & 63, wid = tid >> 6;
    const int r = wid >> 2, eg = wid & 3;      // tok-group, expert-group
    const int fr = lane & 15, hi = lane >> 4;
    const int myg = 2 * eg + r;                // this wave's W chunk

    f32x4 acc0[2][2], acc1[2][2];
#pragma unroll
    for (int i = 0; i < 2; ++i)
#pragma unroll
        for (int j = 0; j < 2; ++j) {
            acc0[i][j] = (f32x4){0.f, 0.f, 0.f, 0.f};
            acc1[i][j] = (f32x4){0.f, 0.f, 0.f, 0.f};
        }

    // A base: row = tok0 + r*32 + fr (+i*16), col = ks*KPER (+kk*32) + hi*8
    const float* xbase = x + (size_t)(tok0 + r * 32 + fr) * DIM + ks * KPER + hi * 8;
    const char*  bsrc0 = wpk + ((size_t)(ks * NST) * 8 + myg) * 4096 + lane * 16;

    float4 xr[4][2];           // [cell c = i*2+kk][half]
    f16x8 ah[4], am[4];

#define XLOAD(ST) { \
    _Pragma("unroll") \
    for (int c = 0; c < 4; ++c) { \
        const float* p = xbase + (size_t)(c >> 1) * 16 * DIM + (c & 1) * 32 + (size_t)(ST) * BK; \
        xr[c][0] = *(const float4*)p; \
        xr[c][1] = *(const float4*)(p + 4); \
    } }
#define XCONV { \
    _Pragma("unroll") \
    for (int c = 0; c < 4; ++c) { \
        union { f16 f[8]; f16x8 v; } ph, pm; \
        split2(xr[c][0].x, ph.f[0], pm.f[0]); split2(xr[c][0].y, ph.f[1], pm.f[1]); \
        split2(xr[c][0].z, ph.f[2], pm.f[2]); split2(xr[c][0].w, ph.f[3], pm.f[3]); \
        split2(xr[c][1].x, ph.f[4], pm.f[4]); split2(xr[c][1].y, ph.f[5], pm.f[5]); \
        split2(xr[c][1].z, ph.f[6], pm.f[6]); split2(xr[c][1].w, ph.f[7], pm.f[7]); \
        ah[c] = ph.v; am[c] = pm.v; \
    } }
#define W_PREF(ST, B) { \
    const char* wsrc = bsrc0 + (size_t)(ST) * 8 * 4096; \
    char* wdst = WB + (B) * 32768 + myg * 4096; \
    gload_lds16(wsrc,        wdst); \
    gload_lds16(wsrc + 1024, wdst + 1024); \
    gload_lds16(wsrc + 2048, wdst + 2048); \
    gload_lds16(wsrc + 3072, wdst + 3072); }
#define COMPUTE(CUR) { \
    _Pragma("unroll") \
    for (int kk = 0; kk < 2; ++kk) \
    _Pragma("unroll") \
    for (int j = 0; j < 2; ++j) { \
        const int wb = (CUR) * 32768 + (2 * eg + j) * 4096 + kk * 1024 + lane * 16; \
        f16x8 bhf = *(const f16x8*)(WB + wb); \
        f16x8 bmf = *(const f16x8*)(WB + wb + 2048); \
        _Pragma("unroll") \
        for (int i = 0; i < 2; ++i) { \
            acc0[i][j] = __builtin_amdgcn_mfma_f32_16x16x32_f16(ah[i * 2 + kk], bhf, acc0[i][j], 0, 0, 0); \
            acc1[i][j] = __builtin_amdgcn_mfma_f32_16x16x32_f16(ah[i * 2 + kk], bmf, acc1[i][j], 0, 0, 0); \
            acc1[i][j] = __builtin_amdgcn_mfma_f32_16x16x32_f16(am[i * 2 + kk], bhf, acc1[i][j], 0, 0, 0); \
        } \
    } }

    // prologue: W[0] (4 gloads) then A[0] (8 loads); vmcnt(8) retires W[0]
    W_PREF(0, 0);
    XLOAD(0);
    asm volatile("s_waitcnt vmcnt(8)" ::: "memory");
    __builtin_amdgcn_s_barrier();
    __builtin_amdgcn_sched_barrier(0);

    for (int st = 0; st < NST; ++st) {
        const int cur = st & 1;
        XCONV;   // consumes xr[st] (compiler waits the A loads, ~1 step old)
        if (st + 1 < NST) {
            W_PREF(st + 1, cur ^ 1);   // 4 gloads, oldest in queue
            XLOAD(st + 1);             // 8 loads behind them
        }
        __builtin_amdgcn_s_setprio(1);
        COMPUTE(cur);
        __builtin_amdgcn_s_setprio(0);
        if (st + 1 < NST) {
            // queue = [W[st+1] x4, A[st+1] x8] -> retire W, keep A in flight
            asm volatile("s_waitcnt vmcnt(8)" ::: "memory");
            __builtin_amdgcn_s_barrier();
            __builtin_amdgcn_sched_barrier(0);
        }
    }

    // epilogue: undo w*64 and m*2048 scales
    float* pbase = partial + ((size_t)ks * NT + tok0 + r * 32) * NEXP;
#pragma unroll
    for (int i = 0; i < 2; ++i)
#pragma unroll
        for (int j = 0; j < 2; ++j)
#pragma unroll
            for (int q = 0; q < 4; ++q) {
                const int row = i * 16 + hi * 4 + q;
                const int e   = eg * 32 + j * 16 + fr;
                pbase[(size_t)row * NEXP + e] =
                    (acc0[i][j][q] + acc1[i][j][q] * (1.0f / 2048.0f)) * (1.0f / 64.0f);
            }
}

// ============ reduce + top-8 + softmax + sel/wgt/counts/blockhist ============
__global__ __launch_bounds__(256)
void topk_kernel(const float* __restrict__ partial, float* __restrict__ wgt,
                 int* __restrict__ sel, int* __restrict__ counts,
                 int* __restrict__ bh) {
    __shared__ float S[32][132];
    __shared__ int h[NEXP];
    const int tid = threadIdx.x;
    const int tok0 = blockIdx.x * 32;
    const int tok = tid >> 3, c = tid & 7;

    f32x4 s0 = {0, 0, 0, 0}, s1 = {0, 0, 0, 0}, s2 = {0, 0, 0, 0}, s3 = {0, 0, 0, 0};
#pragma unroll
    for (int ksq = 0; ksq < KS; ++ksq) {
        const float* p = partial + ((size_t)ksq * NT + tok0 + tok) * NEXP + c * 16;
        s0 += *(const f32x4*)(p);
        s1 += *(const f32x4*)(p + 4);
        s2 += *(const f32x4*)(p + 8);
        s3 += *(const f32x4*)(p + 12);
    }
    *(f32x4*)&S[tok][c * 16]      = s0;
    *(f32x4*)&S[tok][c * 16 + 4]  = s1;
    *(f32x4*)&S[tok][c * 16 + 8]  = s2;
    *(f32x4*)&S[tok][c * 16 + 12] = s3;
    if (tid < NEXP) h[tid] = 0;
    __syncthreads();

    if (tid < 32) {
        float bs[8]; int bi[8];
#pragma unroll
        for (int q = 0; q < 8; ++q) { bs[q] = -3.0e38f; bi[q] = 0; }
        for (int e = 0; e < NEXP; ++e) {
            float s = S[tid][e];
            if (s > bs[7]) {
                int pos = 7;
#pragma unroll
                for (int q = 6; q >= 0; q--) pos = (s > bs[q]) ? q : pos;
#pragma unroll
                for (int q = 7; q >= 1; q--) {
                    bool sh = (q > pos);
                    bs[q] = sh ? bs[q - 1] : bs[q];
                    bi[q] = sh ? bi[q - 1] : bi[q];
                }
#pragma unroll
                for (int q = 0; q < 8; q++)
                    if (q == pos) { bs[q] = s; bi[q] = e; }
            }
        }
        float m = bs[0], sum = 0.f, ex[8];
#pragma unroll
        for (int q = 0; q < 8; ++q) { ex[q] = expf(bs[q] - m); sum += ex[q]; }
        float inv = 1.f / fmaxf(sum, 1e-8f);
        const int tok_g = tok0 + tid;
#pragma unroll
        for (int q = 0; q < 8; ++q) {
            wgt[tok_g * TOPK + q] = ex[q] * inv;
            sel[tok_g * TOPK + q] = bi[q];
            atomicAdd(&h[bi[q]], 1);
        }
    }
    __syncthreads();
    if (tid < NEXP) {
        int cc = h[tid];
        bh[tid * SBLK + blockIdx.x] = cc;
        if (cc) atomicAdd(&counts[tid], cc);
    }
}

// ============ scan: expert bases + per-expert exclusive block-scan ============
__global__ void scan_kernel(const int* __restrict__ bh, const int* __restrict__ counts,
                            int* __restrict__ bo, float* __restrict__ out) {
    const int e = blockIdx.x, tid = threadIdx.x;   // 128 blocks x 512 thr
    __shared__ int pre[NEXP];
    __shared__ int wsum[8];
    if (tid < NEXP) pre[tid] = counts[tid];
    __syncthreads();
#pragma unroll
    for (int d = 1; d < NEXP; d <<= 1) {
        int o = (tid < NEXP && tid >= d) ? pre[tid - d] : 0;
        __syncthreads();
        if (tid < NEXP) pre[tid] += o;
        __syncthreads();
    }
    const int gb = (e == 0) ? 0 : pre[e - 1];
    if (tid == 0) out[2 * NFLAT + e] = (float)counts[e];

    const int lane = tid & 63, wid = tid >> 6;
    int v = bh[e * SBLK + tid];
    int sc = v;
#pragma unroll
    for (int d = 1; d < 64; d <<= 1) {
        int o = __shfl_up(sc, d);
        sc += (lane >= d) ? o : 0;
    }
    if (lane == 63) wsum[wid] = sc;
    __syncthreads();
    int add = 0;
#pragma unroll
    for (int ww = 0; ww < 8; ww++) add += (ww < wid) ? wsum[ww] : 0;
    bo[e * SBLK + tid] = gb + sc - v + add;
}

// ============ scatter: stable in-block rank via 7 ballots ============
__global__ void scatter_kernel(const int* __restrict__ sel, const float* __restrict__ wgt,
                               const int* __restrict__ bo, float* __restrict__ out) {
    const int tid = threadIdx.x, b = blockIdx.x;
    const int i = b * 256 + tid;
    const int e = sel[i];
    const int lane = tid & 63, wid = tid >> 6;
    unsigned long long m = ~0ull;
#pragma unroll
    for (int bit = 0; bit < 7; bit++) {
        unsigned long long bal = __ballot((e >> bit) & 1);
        m &= ((e >> bit) & 1) ? bal : ~bal;
    }
    unsigned long long lower = (lane == 0) ? 0ull : (~0ull >> (64 - lane));
    int wrank = __popcll(m & lower);

    __shared__ int wh_[4][NEXP];
    ((int*)wh_)[tid] = 0; ((int*)wh_)[tid + 256] = 0;
    __syncthreads();
    if (wrank == 0) wh_[wid][e] = __popcll(m);
    __syncthreads();
    int off = 0;
#pragma unroll
    for (int ww = 0; ww < 4; ww++) off += (ww < wid) ? wh_[ww][e] : 0;

    int pos = bo[e * SBLK + b] + off + wrank;
    out[pos] = wgt[i];
    out[NFLAT + pos] = (float)(i >> 3);
}

extern "C" void kernel_launch(void* const* d_in, const int* in_sizes, int n_in,
                              void* d_out, int out_size, void* d_ws, size_t ws_size,
                              hipStream_t stream) {
    const float* x  = (const float*)d_in[0];
    const float* gw = (const float*)d_in[1];
    float* out = (float*)d_out;
    char*  ws  = (char*)d_ws;

    int*   counts  = (int*)(ws + COUNTS_OFF);
    int*   sel     = (int*)(ws + SEL_OFF);
    float* wgt     = (float*)(ws + WGT_OFF);
    int*   bh      = (int*)(ws + BH_OFF);
    int*   bo      = (int*)(ws + BO_OFF);
    char*  wpk     = ws + WPK_OFF;
    float* partial = (float*)(ws + PART_OFF);

    hipMemsetAsync(counts, 0, NEXP * sizeof(int), stream);

    wsplit_kernel<<<256, 256, 0, stream>>>(gw, wpk);
    gemm_kernel<<<512, 512, 0, stream>>>(x, wpk, partial);
    topk_kernel<<<512, 256, 0, stream>>>(partial, wgt, sel, counts, bh);
    scan_kernel<<<NEXP, 512, 0, stream>>>(bh, counts, bo, out);
    scatter_kernel<<<SBLK, 256, 0, stream>>>(sel, wgt, bo, out);
}

// Round 13
// 126.943 us; speedup vs baseline: 1.5541x; 1.5541x over previous
//
#include <hip/hip_runtime.h>
#include <math.h>

typedef _Float16 f16;
typedef f16 f16x8 __attribute__((ext_vector_type(8)));
typedef float f32x4 __attribute__((ext_vector_type(4)));

#define NT    16384
#define DIM   4096
#define NEXP  128
#define TOPK  8
#define NFLAT (NT * TOPK)   // 131072
#define SBLK  512           // sort blocks (256 sel entries each)
#define KS    2             // split-K
#define KPER  (DIM / KS)    // 2048
#define BK    64
#define NST   (KPER / BK)   // 32 steps per block
#define BT    128           // tokens per gemm block

// ---- workspace layout (bytes) ----
#define COUNTS_OFF 0
#define SEL_OFF    1024
#define WGT_OFF    (SEL_OFF + NFLAT * 4)
#define BH_OFF     (WGT_OFF + NFLAT * 4)
#define BO_OFF     (BH_OFF + NEXP * SBLK * 4)
#define WPK_OFF    (BO_OFF + NEXP * SBLK * 4)    // 2 MB packed W
#define PART_OFF   (WPK_OFF + NEXP * DIM * 4)    // 16.8 MB partials

#define G1P __attribute__((address_space(1)))
#define L3P __attribute__((address_space(3)))

__device__ __forceinline__ void gload_lds16(const void* g, void* l) {
    // LDS dest = wave-uniform base + lane*16 (HW); global src = per-lane
    __builtin_amdgcn_global_load_lds((const G1P unsigned int*)g,
                                     (L3P unsigned int*)l, 16, 0, 0);
}

// fp32 -> fp16 high + scaled residual (next ~11 mantissa bits, normal range)
__device__ __forceinline__ void split2(float v, f16& h, f16& m) {
    h = (f16)v;
    m = (f16)((v - (float)h) * 2048.0f);
}

// ============ prologue: pack 64*gw into fragment-ordered f16 chunks ============
// wpk[(st*8+g)*4096 + c*1024 + lane*16]: c0=h,kk0 c1=h,kk1 c2=m,kk0 c3=m,kk1
// content(lane l) = halves of 64*gw[g*16+(l&15)][st*64 + kk*32 + (l>>4)*8 ..+7]
__global__ __launch_bounds__(256)
void wsplit_kernel(const float* __restrict__ gw, char* __restrict__ wpk) {
    const int t = blockIdx.x * 256 + threadIdx.x;    // 65536 threads
    const int l = t & 63, kkc = (t >> 6) & 1, g = (t >> 7) & 7, st = t >> 10;
    const int e = g * 16 + (l & 15);
    const int k0 = st * 64 + kkc * 32 + (l >> 4) * 8;
    float4 a = *(const float4*)&gw[e * 4096 + k0];
    float4 b = *(const float4*)&gw[e * 4096 + k0 + 4];
    union { f16 f[8]; uint4 u; } ph, pm;
    split2(a.x * 64.f, ph.f[0], pm.f[0]); split2(a.y * 64.f, ph.f[1], pm.f[1]);
    split2(a.z * 64.f, ph.f[2], pm.f[2]); split2(a.w * 64.f, ph.f[3], pm.f[3]);
    split2(b.x * 64.f, ph.f[4], pm.f[4]); split2(b.y * 64.f, ph.f[5], pm.f[5]);
    split2(b.z * 64.f, ph.f[6], pm.f[6]); split2(b.w * 64.f, ph.f[7], pm.f[7]);
    const size_t base = ((size_t)(st * 8 + g) * 4 + kkc) * 1024 + l * 16;
    *(uint4*)(wpk + base)        = ph.u;
    *(uint4*)(wpk + base + 2048) = pm.u;
}

// ============ GEMM: partial[ks][tok][e] ============
// 256 blocks = 128 token-tiles x 2 K-slices; 512 thr = 8 waves
// (2 tok-grp x 4 exp-grp); wave tile 64 tok x 32 exp; 32 K-steps of 64.
// A: coalesced global->regs->split2->frag-major swizzled LDS (dbuf 64K).
// W: packed wpk -> global_load_lds (dbuf 64K). One barrier + vmcnt(4)/step.
__global__ __launch_bounds__(512, 2)
void gemm_kernel(const float* __restrict__ x, const char* __restrict__ wpk,
                 float* __restrict__ partial) {
    __shared__ __align__(16) char smem[131072];
    char* WB = smem + 65536;

    const int tid  = threadIdx.x;
    const int bid  = blockIdx.x;
    const int ks   = bid & 1;
    const int tok0 = (bid >> 1) * BT;
    const int lane = tid & 63, wid = tid >> 6;
    const int r = wid >> 2, eg = wid & 3;      // tok-group (64), expert-group (32)
    const int fr = lane & 15, hi = lane >> 4;

    // staging coords: thread covers rows {tid>>3, 64+(tid>>3)}, k-chunk (tid&7)*8
    const int s8  = tid >> 3;                  // 0..63
    const int skq = (tid & 7) * 8;             // 0..56, 8-aligned
    const int xkk = skq >> 5, xhi = (skq >> 3) & 3;
    int xwb[2];
#pragma unroll
    for (int p = 0; p < 2; ++p) {
        const int srow = p * 64 + s8;
        const int xi = srow >> 4, xfr = srow & 15;
        const int slot = xhi * 16 + xfr;
        xwb[p] = ((xi * 2 + xkk) * 64 + (slot ^ ((slot >> 4) << 1))) * 16;
    }
    const int lxs = (lane ^ ((lane >> 4) << 1)) * 16;   // swizzled read slot

    f32x4 acc0[4][2], acc1[4][2];
#pragma unroll
    for (int i = 0; i < 4; ++i)
#pragma unroll
        for (int j = 0; j < 2; ++j) {
            acc0[i][j] = (f32x4){0.f, 0.f, 0.f, 0.f};
            acc1[i][j] = (f32x4){0.f, 0.f, 0.f, 0.f};
        }

    const float* xbase = x + (size_t)(tok0 + s8) * DIM + ks * KPER + skq;
    const char*  bsrc0 = wpk + ((size_t)(ks * NST) * 8 + wid) * 4096 + lane * 16;

#define XLOAD(XR, ST) { \
    _Pragma("unroll") \
    for (int p = 0; p < 2; ++p) { \
        const float* pp = xbase + (size_t)p * 64 * DIM + (size_t)(ST) * BK; \
        XR[p][0] = *(const float4*)pp; \
        XR[p][1] = *(const float4*)(pp + 4); \
    } }
#define W_PREF(ST, B) { \
    const char* wsrc = bsrc0 + (size_t)(ST) * 8 * 4096; \
    char* wdst = WB + (B) * 32768 + wid * 4096; \
    gload_lds16(wsrc,        wdst); \
    gload_lds16(wsrc + 1024, wdst + 1024); \
    gload_lds16(wsrc + 2048, wdst + 2048); \
    gload_lds16(wsrc + 3072, wdst + 3072); }
#define STAGE(CUR, XR) { \
    _Pragma("unroll") \
    for (int p = 0; p < 2; ++p) { \
        union { f16 f[8]; f16x8 v; } ph, pm; \
        split2(XR[p][0].x, ph.f[0], pm.f[0]); split2(XR[p][0].y, ph.f[1], pm.f[1]); \
        split2(XR[p][0].z, ph.f[2], pm.f[2]); split2(XR[p][0].w, ph.f[3], pm.f[3]); \
        split2(XR[p][1].x, ph.f[4], pm.f[4]); split2(XR[p][1].y, ph.f[5], pm.f[5]); \
        split2(XR[p][1].z, ph.f[6], pm.f[6]); split2(XR[p][1].w, ph.f[7], pm.f[7]); \
        *(f16x8*)(smem + (CUR) * 16384 + xwb[p]) = ph.v; \
        *(f16x8*)(smem + 32768 + (CUR) * 16384 + xwb[p]) = pm.v; \
    } }
#define COMPUTE(CUR) { \
    _Pragma("unroll") \
    for (int kk = 0; kk < 2; ++kk) { \
        f16x8 ah[4], am[4]; \
        _Pragma("unroll") \
        for (int i = 0; i < 4; ++i) { \
            const int xb = (CUR) * 16384 + (((r * 4 + i) * 2 + kk) * 64) * 16 + lxs; \
            ah[i] = *(const f16x8*)(smem + xb); \
            am[i] = *(const f16x8*)(smem + 32768 + xb); \
        } \
        _Pragma("unroll") \
        for (int j = 0; j < 2; ++j) { \
            const int wb = (CUR) * 32768 + (2 * eg + j) * 4096 + kk * 1024 + lane * 16; \
            f16x8 bhf = *(const f16x8*)(WB + wb); \
            f16x8 bmf = *(const f16x8*)(WB + wb + 2048); \
            _Pragma("unroll") \
            for (int i = 0; i < 4; ++i) { \
                acc0[i][j] = __builtin_amdgcn_mfma_f32_16x16x32_f16(ah[i], bhf, acc0[i][j], 0, 0, 0); \
                acc1[i][j] = __builtin_amdgcn_mfma_f32_16x16x32_f16(ah[i], bmf, acc1[i][j], 0, 0, 0); \
                acc1[i][j] = __builtin_amdgcn_mfma_f32_16x16x32_f16(am[i], bhf, acc1[i][j], 0, 0, 0); \
            } \
        } \
    } }
// Step invariant: entering STAGE, queue = [W[st]x4, x[st+1]x4]. STAGE's
// compiler wait covers x[st] (already retired). Explicit vmcnt(4) retires
// W[st] (landed in LDS[cur]) keeping x[st+1] in flight. After barrier:
// issue W[st+1] then x[st+2] -> queue [x+1, W+1, x+2]; COMPUTE reads LDS.
#define STEP(CUR, XRC, XRP, PX, PW, SI, VMSTR) { \
    STAGE(CUR, XRC); \
    asm volatile("s_waitcnt lgkmcnt(0) vmcnt(" VMSTR ")" ::: "memory"); \
    __builtin_amdgcn_s_barrier(); \
    __builtin_amdgcn_sched_barrier(0); \
    if (PW) { W_PREF((SI) + 1, (CUR) ^ 1); } \
    if (PX) { XLOAD(XRC, (SI) + 2); } \
    __builtin_amdgcn_s_setprio(1); \
    COMPUTE(CUR); \
    __builtin_amdgcn_s_setprio(0); }

    float4 xr0[2][2], xr1[2][2];
    W_PREF(0, 0);
    XLOAD(xr0, 0);
    XLOAD(xr1, 1);

    for (int st = 0; st < 30; st += 2) {
        STEP(0, xr0, xr1, 1, 1, st, "4");
        STEP(1, xr1, xr0, 1, 1, st + 1, "4");
    }
    STEP(0, xr0, xr1, 0, 1, 30, "4");
    STEP(1, xr1, xr0, 0, 0, 31, "0");

    // epilogue: undo w*64 and m*2048 scales; write partial[ks][tok][e]
    float* pbase = partial + ((size_t)ks * NT + tok0 + r * 64) * NEXP;
#pragma unroll
    for (int i = 0; i < 4; ++i)
#pragma unroll
        for (int j = 0; j < 2; ++j)
#pragma unroll
            for (int q = 0; q < 4; ++q) {
                const int row = i * 16 + hi * 4 + q;
                const int e   = eg * 32 + j * 16 + fr;
                pbase[(size_t)row * NEXP + e] =
                    (acc0[i][j][q] + acc1[i][j][q] * (1.0f / 2048.0f)) * (1.0f / 64.0f);
            }
}

// ============ reduce + top-8 + softmax + sel/wgt/counts/blockhist ============
__global__ __launch_bounds__(256)
void topk_kernel(const float* __restrict__ partial, float* __restrict__ wgt,
                 int* __restrict__ sel, int* __restrict__ counts,
                 int* __restrict__ bh) {
    __shared__ float S[32][132];
    __shared__ int h[NEXP];
    const int tid = threadIdx.x;
    const int tok0 = blockIdx.x * 32;
    const int tok = tid >> 3, c = tid & 7;

    f32x4 s0 = {0, 0, 0, 0}, s1 = {0, 0, 0, 0}, s2 = {0, 0, 0, 0}, s3 = {0, 0, 0, 0};
#pragma unroll
    for (int ksq = 0; ksq < KS; ++ksq) {
        const float* p = partial + ((size_t)ksq * NT + tok0 + tok) * NEXP + c * 16;
        s0 += *(const f32x4*)(p);
        s1 += *(const f32x4*)(p + 4);
        s2 += *(const f32x4*)(p + 8);
        s3 += *(const f32x4*)(p + 12);
    }
    *(f32x4*)&S[tok][c * 16]      = s0;
    *(f32x4*)&S[tok][c * 16 + 4]  = s1;
    *(f32x4*)&S[tok][c * 16 + 8]  = s2;
    *(f32x4*)&S[tok][c * 16 + 12] = s3;
    if (tid < NEXP) h[tid] = 0;
    __syncthreads();

    if (tid < 32) {
        float bs[8]; int bi[8];
#pragma unroll
        for (int q = 0; q < 8; ++q) { bs[q] = -3.0e38f; bi[q] = 0; }
        for (int e = 0; e < NEXP; ++e) {
            float s = S[tid][e];
            if (s > bs[7]) {
                int pos = 7;
#pragma unroll
                for (int q = 6; q >= 0; q--) pos = (s > bs[q]) ? q : pos;
#pragma unroll
                for (int q = 7; q >= 1; q--) {
                    bool sh = (q > pos);
                    bs[q] = sh ? bs[q - 1] : bs[q];
                    bi[q] = sh ? bi[q - 1] : bi[q];
                }
#pragma unroll
                for (int q = 0; q < 8; q++)
                    if (q == pos) { bs[q] = s; bi[q] = e; }
            }
        }
        float m = bs[0], sum = 0.f, ex[8];
#pragma unroll
        for (int q = 0; q < 8; ++q) { ex[q] = expf(bs[q] - m); sum += ex[q]; }
        float inv = 1.f / fmaxf(sum, 1e-8f);
        const int tok_g = tok0 + tid;
#pragma unroll
        for (int q = 0; q < 8; ++q) {
            wgt[tok_g * TOPK + q] = ex[q] * inv;
            sel[tok_g * TOPK + q] = bi[q];
            atomicAdd(&h[bi[q]], 1);
        }
    }
    __syncthreads();
    if (tid < NEXP) {
        int cc = h[tid];
        bh[tid * SBLK + blockIdx.x] = cc;
        if (cc) atomicAdd(&counts[tid], cc);
    }
}

// ============ scan: expert bases + per-expert exclusive block-scan ============
__global__ void scan_kernel(const int* __restrict__ bh, const int* __restrict__ counts,
                            int* __restrict__ bo, float* __restrict__ out) {
    const int e = blockIdx.x, tid = threadIdx.x;   // 128 blocks x 512 thr
    __shared__ int pre[NEXP];
    __shared__ int wsum[8];
    if (tid < NEXP) pre[tid] = counts[tid];
    __syncthreads();
#pragma unroll
    for (int d = 1; d < NEXP; d <<= 1) {
        int o = (tid < NEXP && tid >= d) ? pre[tid - d] : 0;
        __syncthreads();
        if (tid < NEXP) pre[tid] += o;
        __syncthreads();
    }
    const int gb = (e == 0) ? 0 : pre[e - 1];
    if (tid == 0) out[2 * NFLAT + e] = (float)counts[e];

    const int lane = tid & 63, wid = tid >> 6;
    int v = bh[e * SBLK + tid];
    int sc = v;
#pragma unroll
    for (int d = 1; d < 64; d <<= 1) {
        int o = __shfl_up(sc, d);
        sc += (lane >= d) ? o : 0;
    }
    if (lane == 63) wsum[wid] = sc;
    __syncthreads();
    int add = 0;
#pragma unroll
    for (int ww = 0; ww < 8; ww++) add += (ww < wid) ? wsum[ww] : 0;
    bo[e * SBLK + tid] = gb + sc - v + add;
}

// ============ scatter: stable in-block rank via 7 ballots ============
__global__ void scatter_kernel(const int* __restrict__ sel, const float* __restrict__ wgt,
                               const int* __restrict__ bo, float* __restrict__ out) {
    const int tid = threadIdx.x, b = blockIdx.x;
    const int i = b * 256 + tid;
    const int e = sel[i];
    const int lane = tid & 63, wid = tid >> 6;
    unsigned long long m = ~0ull;
#pragma unroll
    for (int bit = 0; bit < 7; bit++) {
        unsigned long long bal = __ballot((e >> bit) & 1);
        m &= ((e >> bit) & 1) ? bal : ~bal;
    }
    unsigned long long lower = (lane == 0) ? 0ull : (~0ull >> (64 - lane));
    int wrank = __popcll(m & lower);

    __shared__ int wh_[4][NEXP];
    ((int*)wh_)[tid] = 0; ((int*)wh_)[tid + 256] = 0;
    __syncthreads();
    if (wrank == 0) wh_[wid][e] = __popcll(m);
    __syncthreads();
    int off = 0;
#pragma unroll
    for (int ww = 0; ww < 4; ww++) off += (ww < wid) ? wh_[ww][e] : 0;

    int pos = bo[e * SBLK + b] + off + wrank;
    out[pos] = wgt[i];
    out[NFLAT + pos] = (float)(i >> 3);
}

extern "C" void kernel_launch(void* const* d_in, const int* in_sizes, int n_in,
                              void* d_out, int out_size, void* d_ws, size_t ws_size,
                              hipStream_t stream) {
    const float* x  = (const float*)d_in[0];
    const float* gw = (const float*)d_in[1];
    float* out = (float*)d_out;
    char*  ws  = (char*)d_ws;

    int*   counts  = (int*)(ws + COUNTS_OFF);
    int*   sel     = (int*)(ws + SEL_OFF);
    float* wgt     = (float*)(ws + WGT_OFF);
    int*   bh      = (int*)(ws + BH_OFF);
    int*   bo      = (int*)(ws + BO_OFF);
    char*  wpk     = ws + WPK_OFF;
    float* partial = (float*)(ws + PART_OFF);

    hipMemsetAsync(counts, 0, NEXP * sizeof(int), stream);

    wsplit_kernel<<<256, 256, 0, stream>>>(gw, wpk);
    gemm_kernel<<<256, 512, 0, stream>>>(x, wpk, partial);
    topk_kernel<<<512, 256, 0, stream>>>(partial, wgt, sel, counts, bh);
    scan_kernel<<<NEXP, 512, 0, stream>>>(bh, counts, bo, out);
    scatter_kernel<<<SBLK, 256, 0, stream>>>(sel, wgt, bo, out);
}